// Round 8
// baseline (147.302 us; speedup 1.0000x reference)
//
#include <hip/hip_runtime.h>

// Problem constants (from reference setup_inputs)
#define BATCH 256
#define SEQ   2048
#define VOCAB 128000
#define HASH  4096    // dedup hash: 2x SEQ, load factor 0.5
#define CHUNK 4096    // vocab slots per consumer block, 2^12
#define CPR   32      // chunks per row: ceil(128000/4096) (last chunk = 1024)
#define CAP   128     // pair capacity per (row,chunk) bucket; mean ~65, sd ~8

typedef float v2f __attribute__((ext_vector_type(2)));
typedef int   v2i __attribute__((ext_vector_type(2)));
typedef float v4f __attribute__((ext_vector_type(4)));
typedef int   v4i __attribute__((ext_vector_type(4)));

// ---------------- Kernel A: per-row softmax + dedup + bucketed winner lists ----
// One block per row, 1024 threads. Each thread owns 2 positions. CAS-hash
// dedup (last position wins = numpy fancy-assignment semantics), winners
// compacted into per-(row,chunk) buckets in workspace.
__global__ __launch_bounds__(1024, 4)
void rowprep_kernel(const float* __restrict__ w_es,
                    const int*   __restrict__ x,
                    float* __restrict__ w_out,    // [BATCH, SEQ]
                    int*   __restrict__ counts,   // [BATCH*CPR]
                    int2*  __restrict__ pairs)    // [BATCH*CPR*CAP]
{
    __shared__ int   key [HASH];
    __shared__ int   maxi[HASH];
    __shared__ int   cnt [CPR];
    __shared__ float redm[16], reds[16];

    const int r = blockIdx.x;
    const int t = threadIdx.x;
    const int lane = t & 63;
    const int wid  = t >> 6;       // 16 waves

    for (int j = t; j < HASH; j += 1024) { key[j] = -1; maxi[j] = -1; }
    if (t < CPR) cnt[t] = 0;

    // ---- load scores (positions 2t, 2t+1) and tokens; both issue early ----
    const float* rowp = w_es + (size_t)r * SEQ;
    const v2f a = ((const v2f*)rowp)[t];
    const int* xrow = x + (size_t)r * SEQ;
    const v2i xt = ((const v2i*)xrow)[t];

    // ---- block max ----
    float m = fmaxf(a.x, a.y);
    #pragma unroll
    for (int off = 32; off > 0; off >>= 1)
        m = fmaxf(m, __shfl_down(m, off, 64));
    if (lane == 0) redm[wid] = m;
    __syncthreads();               // also covers LDS init visibility
    #pragma unroll
    for (int j = 0; j < 16; ++j) m = fmaxf(m, redm[j]);

    // ---- exp + block sum ----
    float e0 = __expf(a.x - m), e1 = __expf(a.y - m);
    float s = e0 + e1;
    #pragma unroll
    for (int off = 32; off > 0; off >>= 1)
        s += __shfl_down(s, off, 64);
    if (lane == 0) reds[wid] = s;
    __syncthreads();
    s = 0.0f;
    #pragma unroll
    for (int j = 0; j < 16; ++j) s += reds[j];

    const float inv = 1.0f / s;
    float w[2] = { e0 * inv, e1 * inv };

    // ---- weights output (coalesced 8B) ----
    float* wrow = w_out + (size_t)r * SEQ;
    v2f wv; wv.x = w[0]; wv.y = w[1];
    ((v2f*)wrow)[t] = wv;

    int tok[2] = { xt.x, xt.y };
    int idx[2] = { 2 * t, 2 * t + 1 };

    // ---- dedup via CAS hash; slots write-once so all holders of a token
    //      converge to one slot; atomicMax tracks the last position ----
    int slot[2];
    #pragma unroll
    for (int k = 0; k < 2; ++k) {
        unsigned h = (((unsigned)tok[k] * 2654435761u) >> 16) & (HASH - 1);
        int sl = (int)h;
        while (true) {
            int prev = atomicCAS(&key[sl], -1, tok[k]);
            if (prev == -1 || prev == tok[k]) break;
            sl = (sl + 1) & (HASH - 1);
        }
        slot[k] = sl;
        atomicMax(&maxi[sl], idx[k]);
    }
    __syncthreads();

    // ---- winners -> bucketed compact lists in workspace ----
    #pragma unroll
    for (int k = 0; k < 2; ++k) {
        if (maxi[slot[k]] == idx[k]) {
            int c   = tok[k] >> 12;                 // chunk id (CHUNK = 2^12)
            int pos = atomicAdd(&cnt[c], 1);
            if (pos < CAP)
                pairs[(size_t)(r * CPR + c) * CAP + pos] =
                    make_int2(tok[k] & (CHUNK - 1), __float_as_int(w[k]));
        }
    }
    __syncthreads();
    if (t < CPR) counts[r * CPR + t] = min(cnt[t], CAP);
}

// ---------------- Kernel B: direct fill + in-L2 scatter, no LDS --------------
// Block bid=(r,c): fill its 16 KB window of w_a with zeros (coalesced v4
// stores, exactly the fill-kernel pattern that measures 6.7 TB/s), barrier
// (drains vmcnt -> zeros complete at L2), then scatter <=CAP pre-deduped
// winners as dword stores into the same window. Window lines are still
// L2-resident (footprint/XCD ~= 4 MB), so HBM sees each line once.
__global__ __launch_bounds__(256)
void fillscatter_kernel(const int*  __restrict__ counts,
                        const int2* __restrict__ pairs,
                        float* __restrict__ w_a)      // [BATCH, VOCAB]
{
    const int bid = blockIdx.x;
    const int r = bid >> 5;
    const int c = bid & (CPR - 1);
    const int base = c * CHUNK;
    const int cnt  = (VOCAB - base < CHUNK) ? (VOCAB - base) : CHUNK; // 4096 or 1024
    const int cnt4 = cnt >> 2;     // 1024 or 256, both divisible by 256
    const int t = threadIdx.x;

    // issue bucket loads immediately; they complete during the fill
    int2 pr = make_int2(0, 0);
    if (t < CAP) pr = pairs[(size_t)bid * CAP + t];
    const int n = counts[bid];

    float* gp = w_a + (size_t)r * VOCAB + base;
    const v4f z = (v4f)0.0f;
    for (int j = t; j < cnt4; j += 256)
        ((v4f*)gp)[j] = z;

    __syncthreads();   // zeros drained to L2 before scatter (same-addr order)

    if (t < n)
        gp[pr.x] = __int_as_float(pr.y);   // distinct slots -> no races
}

extern "C" void kernel_launch(void* const* d_in, const int* in_sizes, int n_in,
                              void* d_out, int out_size, void* d_ws, size_t ws_size,
                              hipStream_t stream) {
    const float* w_es = (const float*)d_in[0];
    const int*   x    = (const int*)d_in[1];

    float* out  = (float*)d_out;
    float* w_a  = out;                          // [256, 128000]
    float* w    = out + (size_t)BATCH * VOCAB;  // [256, 2048]

    // workspace layout: counts (32 KB) then pairs (8 MB)
    int*  counts = (int*)d_ws;
    int2* pairs  = (int2*)((char*)d_ws + BATCH * CPR * sizeof(int));

    rowprep_kernel    <<<BATCH,       1024, 0, stream>>>(w_es, x, w, counts, pairs);
    fillscatter_kernel<<<BATCH * CPR, 256,  0, stream>>>(counts, pairs, w_a);
}

// Round 9
// 142.969 us; speedup vs baseline: 1.0303x; 1.0303x over previous
//
#include <hip/hip_runtime.h>

// Problem constants (from reference setup_inputs)
#define BATCH 256
#define SEQ   2048
#define VOCAB 128000
#define HASH  4096    // dedup hash: 2x SEQ, load factor 0.5

typedef float v2f __attribute__((ext_vector_type(2)));
typedef int   v2i __attribute__((ext_vector_type(2)));
typedef float v4f __attribute__((ext_vector_type(4)));

// Single kernel, one block per row (grid = 256 = CU count), 1024 threads.
//   1. Issue the row's entire 500 KB zero-fill immediately (coalesced v4f
//      stores, the pattern that measures 6.7 TB/s). These drain in the
//      background for the rest of the kernel.
//   2. Softmax over the row (shuffle + LDS reduce) while stores drain.
//   3. CAS-hash dedup (last position wins = numpy fancy-assignment).
//   4. __syncthreads() — compiler emits s_waitcnt vmcnt(0) before s_barrier,
//      so every fill store in the block is complete; same-address ordering
//      with the scatter below is therefore guaranteed.
//   5. Scatter ~2035 winner weights as dword stores into the row.
// Every w_a byte is written exactly once (plus ~64B RFO per winner line).
__global__ __launch_bounds__(1024, 4)
void fused_row_kernel(const float* __restrict__ w_es,
                      const int*   __restrict__ x,
                      float* __restrict__ w_a,      // [BATCH, VOCAB]
                      float* __restrict__ w_out)    // [BATCH, SEQ]
{
    __shared__ int   key [HASH];
    __shared__ int   maxi[HASH];
    __shared__ float redm[16], reds[16];

    const int r = blockIdx.x;
    const int t = threadIdx.x;
    const int lane = t & 63;
    const int wid  = t >> 6;       // 16 waves

    // ---- (1) zero-fill this row of w_a: 32000 v4f stores over 1024 threads.
    // Issued first so the write pipe saturates while we compute. ----
    float* grow = w_a + (size_t)r * VOCAB;
    {
        const v4f z = (v4f)0.0f;
        #pragma unroll 4
        for (int j = t; j < (VOCAB / 4); j += 1024)
            ((v4f*)grow)[j] = z;
    }

    // ---- input loads (issue early) ----
    const float* rowp = w_es + (size_t)r * SEQ;
    const v2f a = ((const v2f*)rowp)[t];
    const int* xrow = x + (size_t)r * SEQ;
    const v2i xt = ((const v2i*)xrow)[t];

    // ---- hash init ----
    for (int j = t; j < HASH; j += 1024) { key[j] = -1; maxi[j] = -1; }

    // ---- (2) softmax: block max ----
    float m = fmaxf(a.x, a.y);
    #pragma unroll
    for (int off = 32; off > 0; off >>= 1)
        m = fmaxf(m, __shfl_down(m, off, 64));
    if (lane == 0) redm[wid] = m;
    __syncthreads();               // also covers hash-init visibility
    #pragma unroll
    for (int j = 0; j < 16; ++j) m = fmaxf(m, redm[j]);

    // ---- exp + block sum ----
    float e0 = __expf(a.x - m), e1 = __expf(a.y - m);
    float s = e0 + e1;
    #pragma unroll
    for (int off = 32; off > 0; off >>= 1)
        s += __shfl_down(s, off, 64);
    if (lane == 0) reds[wid] = s;
    __syncthreads();
    s = 0.0f;
    #pragma unroll
    for (int j = 0; j < 16; ++j) s += reds[j];

    const float inv = 1.0f / s;
    float w0 = e0 * inv, w1 = e1 * inv;

    // ---- weights output (coalesced 8B) ----
    {
        v2f wv; wv.x = w0; wv.y = w1;
        ((v2f*)(w_out + (size_t)r * SEQ))[t] = wv;
    }

    // ---- (3) dedup via CAS hash; slots are write-once so all holders of a
    // token converge to one slot; atomicMax tracks the last position ----
    int tok[2] = { xt.x, xt.y };
    int idx[2] = { 2 * t, 2 * t + 1 };
    float wv2[2] = { w0, w1 };
    int slot[2];
    #pragma unroll
    for (int k = 0; k < 2; ++k) {
        unsigned h = (((unsigned)tok[k] * 2654435761u) >> 16) & (HASH - 1);
        int sl = (int)h;
        while (true) {
            int prev = atomicCAS(&key[sl], -1, tok[k]);
            if (prev == -1 || prev == tok[k]) break;
            sl = (sl + 1) & (HASH - 1);
        }
        slot[k] = sl;
        atomicMax(&maxi[sl], idx[k]);
    }

    // ---- (4) barrier: drains vmcnt(0) -> all fill stores complete; also
    // publishes maxi[] ----
    __syncthreads();

    // ---- (5) winners scatter directly into the row ----
    #pragma unroll
    for (int k = 0; k < 2; ++k)
        if (maxi[slot[k]] == idx[k])
            grow[tok[k]] = wv2[k];
}

extern "C" void kernel_launch(void* const* d_in, const int* in_sizes, int n_in,
                              void* d_out, int out_size, void* d_ws, size_t ws_size,
                              hipStream_t stream) {
    const float* w_es = (const float*)d_in[0];
    const int*   x    = (const int*)d_in[1];

    float* out  = (float*)d_out;
    float* w_a  = out;                          // [256, 128000]
    float* w    = out + (size_t)BATCH * VOCAB;  // [256, 2048]

    fused_row_kernel<<<BATCH, 1024, 0, stream>>>(w_es, x, w_a, w);
}